// Round 5
// baseline (265.795 us; speedup 1.0000x reference)
//
#include <hip/hip_runtime.h>
#include <cstdint>
#include <cstddef>

// Problem constants
#define DMODEL 1024
#define HEADS  16
#define DHEAD  64
#define BATCH  4
#define SEQ    2048
#define ROWS   (BATCH * SEQ)          // 8192
#define INV_DSCALE 0.3535533905932738f // 1 / 64^(1/4)

typedef float  f32x4  __attribute__((ext_vector_type(4)));
typedef __bf16 bf16x8 __attribute__((ext_vector_type(8)));

__device__ __forceinline__ unsigned short f2bf(float x) {
    union { float f; unsigned u; } c; c.f = x;
    unsigned u = c.u;
    return (unsigned short)((u + 0x7fffu + ((u >> 16) & 1u)) >> 16);
}

// Pack two f32 -> packed 2x bf16 (RNE).
__device__ __forceinline__ unsigned cvt_pk_bf16(float a, float b) {
#if __has_builtin(__builtin_amdgcn_cvt_pk_bf16_f32)
    typedef __bf16 bf16x2_t __attribute__((ext_vector_type(2)));
    union { bf16x2_t v; unsigned u; } c;
    c.v = __builtin_amdgcn_cvt_pk_bf16_f32(a, b);
    return c.u;
#else
    return (unsigned)f2bf(a) | ((unsigned)f2bf(b) << 16);
#endif
}

__device__ __forceinline__ void load_g2l16(const unsigned short* g, unsigned short* l) {
    __builtin_amdgcn_global_load_lds(
        (const __attribute__((address_space(1))) unsigned int*)g,
        (__attribute__((address_space(3))) unsigned int*)l,
        16 /*bytes*/, 0 /*offset*/, 0 /*aux*/);
}

// ---------------------------------------------------------------------------
// Weight prep + x cast:
//   blocks [0,768)      pack Wq/Wk/Wv -> [n=h*64+d][k=m] bf16
//   blocks [768,1792)   straight-cast Wo
//   blocks [1792,7936)  cast xq/xk/xv fp32 -> Xb bf16, 2 groups/thread
__global__ __launch_bounds__(256) void prep_w(const float* __restrict__ W0,
                                              const float* __restrict__ W1,
                                              const float* __restrict__ W2,
                                              const float* __restrict__ Wo,
                                              const float* __restrict__ Xq,
                                              const float* __restrict__ Xk,
                                              const float* __restrict__ Xv,
                                              unsigned short* __restrict__ T0,
                                              unsigned short* __restrict__ T1,
                                              unsigned short* __restrict__ T2,
                                              unsigned short* __restrict__ To,
                                              unsigned short* __restrict__ Xb) {
    __shared__ float tile[64][68];
    int blk = blockIdx.x;
    int t = threadIdx.x;
    if (blk < 768) {
        int w = blk >> 8, h = (blk >> 4) & 15, mb = blk & 15;
        const float* W = w == 0 ? W0 : (w == 1 ? W1 : W2);
        unsigned short* T = w == 0 ? T0 : (w == 1 ? T1 : T2);
        #pragma unroll
        for (int i = 0; i < 4; ++i) {
            int f = t + 256 * i;
            int m = f >> 4, dg = (f & 15) * 4;
            *(float4*)&tile[m][dg] = *(const float4*)&W[((size_t)(h * 16 + mb) * 64 + m) * 64 + dg];
        }
        __syncthreads();
        #pragma unroll
        for (int i = 0; i < 2; ++i) {
            int f = t + 256 * i;
            int d = f >> 3, mg = f & 7;
            ushort4 a, b;
            a.x = f2bf(tile[mg * 8 + 0][d]); a.y = f2bf(tile[mg * 8 + 1][d]);
            a.z = f2bf(tile[mg * 8 + 2][d]); a.w = f2bf(tile[mg * 8 + 3][d]);
            b.x = f2bf(tile[mg * 8 + 4][d]); b.y = f2bf(tile[mg * 8 + 5][d]);
            b.z = f2bf(tile[mg * 8 + 6][d]); b.w = f2bf(tile[mg * 8 + 7][d]);
            unsigned short* dst = T + (size_t)(h * 64 + d) * DMODEL + mb * 64 + mg * 8;
            *(ushort4*)dst = a; *(ushort4*)(dst + 4) = b;
        }
    } else if (blk < 1792) {
        int i = (blk - 768) * 256 + t;
        float4 v = ((const float4*)Wo)[i];
        ushort4 o;
        o.x = f2bf(v.x); o.y = f2bf(v.y); o.z = f2bf(v.z); o.w = f2bf(v.w);
        ((ushort4*)To)[i] = o;
    } else {
        // x cast: 2048 blocks per z, 2 groups of 8 elems per thread
        int bb = blk - 1792;
        int w = bb >> 11;
        int g0 = (bb & 2047) * 256 + t;         // [0, 524288)
        const float* X = w == 0 ? Xq : (w == 1 ? Xk : Xv);
        unsigned short* D = Xb + (size_t)w * ROWS * DMODEL;
        #pragma unroll
        for (int u = 0; u < 2; ++u) {
            size_t g = (size_t)g0 + (size_t)u * 524288;
            const float4* src = (const float4*)X + g * 2;
            float4 a = src[0], bv = src[1];
            uint4 pk;
            pk.x = cvt_pk_bf16(a.x, a.y);
            pk.y = cvt_pk_bf16(a.z, a.w);
            pk.z = cvt_pk_bf16(bv.x, bv.y);
            pk.w = cvt_pk_bf16(bv.z, bv.w);
            ((uint4*)D)[g] = pk;
        }
    }
}

// ---------------------------------------------------------------------------
// m97-structure GEMM tile: 128x128, BK=64, 4 waves each 64x64 (4x4 of
// 16x16x32). XOR swizzle: LDS slot (row, s) holds global k-group s ^ (row&7).
// A and B both bf16 in global, staged via global_load_lds width-16.
__device__ __forceinline__ void gemm_tile(const unsigned short* __restrict__ Ap,
                                          const unsigned short* __restrict__ Bp,
                                          int K, int bm0, int bn0,
                                          unsigned short* smem, f32x4 acc[4][4]) {
    unsigned short* ldsA = smem;            // 128*64 u16 = 16 KB
    unsigned short* ldsB = smem + 8192;     // 128*64 u16 = 16 KB

    const int t    = threadIdx.x;
    const int lane = t & 63;
    const int wave = t >> 6;
    const int wm   = (wave & 1) * 64;
    const int wn   = (wave >> 1) * 64;
    const int fr   = lane & 15;
    const int quad = lane >> 4;

    unsigned offA[4], offB[4];
    #pragma unroll
    for (int i = 0; i < 4; ++i) {
        int f = t + 256 * i, row = f >> 3, kg = (f & 7) ^ (row & 7);
        offA[i] = (unsigned)(bm0 + row) * K + kg * 8;
        offB[i] = (unsigned)(bn0 + row) * K + kg * 8;
    }

    for (int k0 = 0; k0 < K; k0 += 64) {
        #pragma unroll
        for (int i = 0; i < 4; ++i)
            load_g2l16(Ap + offA[i] + k0, &ldsA[(t + 256 * i) * 8]);
        #pragma unroll
        for (int i = 0; i < 4; ++i)
            load_g2l16(Bp + offB[i] + k0, &ldsB[(t + 256 * i) * 8]);
        asm volatile("s_waitcnt vmcnt(0)" ::: "memory");
        __syncthreads();

        bf16x8 af[4][2], bfr[4][2];
        #pragma unroll
        for (int i = 0; i < 4; ++i) {
            int row = wm + i * 16 + fr;
            #pragma unroll
            for (int kh = 0; kh < 2; ++kh) {
                int s = (kh * 4 + quad) ^ (row & 7);
                af[i][kh] = *reinterpret_cast<const bf16x8*>(&ldsA[row * 64 + s * 8]);
            }
        }
        #pragma unroll
        for (int j = 0; j < 4; ++j) {
            int row = wn + j * 16 + fr;
            #pragma unroll
            for (int kh = 0; kh < 2; ++kh) {
                int s = (kh * 4 + quad) ^ (row & 7);
                bfr[j][kh] = *reinterpret_cast<const bf16x8*>(&ldsB[row * 64 + s * 8]);
            }
        }
        #pragma unroll
        for (int kh = 0; kh < 2; ++kh)
            #pragma unroll
            for (int i = 0; i < 4; ++i)
                #pragma unroll
                for (int j = 0; j < 4; ++j)
                    acc[i][j] = __builtin_amdgcn_mfma_f32_16x16x32_bf16(af[i][kh], bfr[j][kh], acc[i][j], 0, 0, 0);

        __syncthreads();
    }
}

// Fused 64-wide head-group softmax over the wave's 4 j-frags (one head).
__device__ __forceinline__ void softmax4(float v[4]) {
    #pragma unroll
    for (int j = 0; j < 4; ++j) v[j] *= INV_DSCALE;
    float m = fmaxf(fmaxf(v[0], v[1]), fmaxf(v[2], v[3]));
    #pragma unroll
    for (int off = 8; off; off >>= 1) m = fmaxf(m, __shfl_xor(m, off, 16));
    float s = 0.f;
    #pragma unroll
    for (int j = 0; j < 4; ++j) { v[j] = __expf(v[j] - m); s += v[j]; }
    #pragma unroll
    for (int off = 8; off; off >>= 1) s += __shfl_xor(s, off, 16);
    float inv = 1.0f / s;
    #pragma unroll
    for (int j = 0; j < 4; ++j) v[j] *= inv;
}

// XCD-aware decode for 512 blocks (64 m-blocks x 8 n-blocks of a 128x128 tile)
__device__ __forceinline__ void decode_blk(int flat, int& bm0, int& bn0) {
    int xcd = flat & 7, idx = flat >> 3;        // idx in [0,64)
    bm0 = (xcd * 8 + (idx >> 3)) * 128;
    bn0 = (idx & 7) * 128;
}

// ---------------------------------------------------------------------------
// K/V projections. y=0 -> z=1: K -> softmax -> TRANSPOSED Kt[bh][d][s].
// y=1 -> z=2: V -> TRANSPOSED Vt[bh][e][s].
__global__ __launch_bounds__(256, 2) void proj_kv(const unsigned short* __restrict__ Xb,
                                                  const unsigned short* __restrict__ wk,
                                                  const unsigned short* __restrict__ wv,
                                                  unsigned short* __restrict__ Kt,
                                                  unsigned short* __restrict__ Vt) {
    __shared__ unsigned short smem[17408];      // gemm staging (32 KB), then Ct (128*136)
    int z = blockIdx.y + 1;
    const unsigned short* A = Xb + (size_t)z * ROWS * DMODEL;
    const unsigned short* B = (z == 1) ? wk : wv;
    int bm0, bn0;
    decode_blk(blockIdx.x, bm0, bn0);

    f32x4 acc[4][4] = {};
    gemm_tile(A, B, DMODEL, bm0, bn0, smem, acc);

    const int t    = threadIdx.x;
    const int lane = t & 63;
    const int wave = t >> 6;
    const int wm   = (wave & 1) * 64;
    const int wn   = (wave >> 1) * 64;
    const int fr   = lane & 15;
    const int quad = lane >> 4;
    bool do_sm = (z == 1);

    // transpose epilogue: Ct[col][s_local], pitch 136 (16B-aligned rows)
    unsigned short* Ct = smem;              // 128*136 u16 = 34.8 KB
    #pragma unroll
    for (int i = 0; i < 4; ++i)
        #pragma unroll
        for (int r = 0; r < 4; ++r) {
            float v[4];
            #pragma unroll
            for (int j = 0; j < 4; ++j) v[j] = acc[i][j][r];
            if (do_sm) softmax4(v);
            int rr = wm + i * 16 + quad * 4 + r;          // s_local 0..127
            #pragma unroll
            for (int j = 0; j < 4; ++j) {
                int cc = wn + j * 16 + fr;                // col 0..127
                Ct[cc * 136 + rr] = f2bf(v[j]);
            }
        }
    __syncthreads();
    // coalesced-per-row copy out: thread t handles col c = t>>1, s-half (t&1)*64
    unsigned short* T = (z == 1) ? Kt : Vt;
    int c = t >> 1, sh = (t & 1) * 64;
    int col = bn0 + c, h = col >> 6, d = col & 63;
    int b = bm0 >> 11, s0 = bm0 & 2047;
    unsigned short* dst = T + (((size_t)(b * 16 + h) * 64 + d) << 11) + s0 + sh;
    const unsigned short* src = &smem[c * 136 + sh];
    #pragma unroll
    for (int k = 0; k < 8; ++k)
        *(uint4*)(dst + k * 8) = *(const uint4*)(src + k * 8);
}

// ---------------------------------------------------------------------------
// Q projection FUSED with xAt: R[bh][s][e] = softmax(Q)[s,:] . At[bh][e,:]
// Each block: 128 rows x 2 heads. Qs -> LDS (swizzled), At staged via
// global_load_lds (pre-swizzled source), 32 MFMA/wave epilogue, write R.
__global__ __launch_bounds__(256, 2) void proj_q(const unsigned short* __restrict__ Xb,
                                                 const unsigned short* __restrict__ wq,
                                                 const unsigned short* __restrict__ At,
                                                 unsigned short* __restrict__ R) {
    __shared__ unsigned short smem[24576];   // 48 KB: 32 KB staging/Qs + 16 KB At
    int bm0, bn0;
    decode_blk(blockIdx.x, bm0, bn0);

    f32x4 acc[4][4] = {};
    gemm_tile(Xb, wq, DMODEL, bm0, bn0, smem, acc);

    const int t = threadIdx.x, lane = t & 63, wave = t >> 6;
    const int wm = (wave & 1) * 64, wn = (wave >> 1) * 64;
    const int fr = lane & 15, quad = lane >> 4;
    const int b = bm0 >> 11, s0 = bm0 & 2047;
    const int h0 = bn0 >> 6;                 // first of two heads in this block
    const int bh_base = b * 16 + h0;

    unsigned short* Qs = smem;               // [128][128] u16, XOR-swizzled per 64-col panel
    unsigned short* ldsAt = smem + 16384;    // [2][64*64]

    // stage At for the block's two heads (swizzled source, linear dest)
    #pragma unroll
    for (int i = 0; i < 4; ++i) {
        int f = t + 256 * i;                 // 0..1023 groups of 8
        int hd = f >> 9, row = (f >> 3) & 63, kg = (f & 7) ^ (row & 7);
        load_g2l16(At + (size_t)(bh_base + hd) * 4096 + row * 64 + kg * 8,
                   &ldsAt[f * 8]);
    }

    // softmax + write Qs tile to LDS (swizzled within each 64-col panel)
    #pragma unroll
    for (int i = 0; i < 4; ++i)
        #pragma unroll
        for (int r = 0; r < 4; ++r) {
            float v[4];
            #pragma unroll
            for (int j = 0; j < 4; ++j) v[j] = acc[i][j][r];
            softmax4(v);
            int row = wm + i * 16 + quad * 4 + r;
            #pragma unroll
            for (int j = 0; j < 4; ++j) {
                int c = wn + j * 16 + fr;
                int cs = (c & 0x47) | (((((c >> 3) & 7) ^ (row & 7))) << 3);
                Qs[row * 128 + cs] = f2bf(v[j]);
            }
        }
    asm volatile("s_waitcnt vmcnt(0)" ::: "memory");
    __syncthreads();

    // R-tile = Qs(64 rows x 64 d, head hw) x At[hw] ([e][d] operand)
    const int hw = wn >> 6;
    f32x4 racc[4][4] = {};
    #pragma unroll
    for (int kh = 0; kh < 2; ++kh) {
        bf16x8 aq[4], bt[4];
        #pragma unroll
        for (int i = 0; i < 4; ++i) {
            int row = wm + i * 16 + fr;
            int s = (kh * 4 + quad) ^ (row & 7);
            aq[i] = *reinterpret_cast<const bf16x8*>(&Qs[row * 128 + wn + s * 8]);
        }
        #pragma unroll
        for (int j = 0; j < 4; ++j) {
            int e = j * 16 + fr;
            int s = (kh * 4 + quad) ^ (e & 7);
            bt[j] = *reinterpret_cast<const bf16x8*>(&ldsAt[(hw << 12) + e * 64 + s * 8]);
        }
        #pragma unroll
        for (int i = 0; i < 4; ++i)
            #pragma unroll
            for (int j = 0; j < 4; ++j)
                racc[i][j] = __builtin_amdgcn_mfma_f32_16x16x32_bf16(aq[i], bt[j], racc[i][j], 0, 0, 0);
    }

    // write R flat [b,h,s,e]
    size_t bh = (size_t)(bh_base + hw);
    #pragma unroll
    for (int i = 0; i < 4; ++i)
        #pragma unroll
        for (int r = 0; r < 4; ++r) {
            int rr = wm + i * 16 + quad * 4 + r;         // s_local within 128
            size_t base = (bh << 17) + (size_t)(s0 + rr) * 64;
            #pragma unroll
            for (int j = 0; j < 4; ++j)
                R[base + j * 16 + fr] = f2bf(racc[i][j][r]);
        }
}

// out = R (bf16 [8192,1024] flat) @ Wo^T -> fp32
__global__ __launch_bounds__(256, 2) void gemm_out(const unsigned short* __restrict__ R,
                                                   const unsigned short* __restrict__ Wo,
                                                   float* __restrict__ out) {
    __shared__ unsigned short smem[16384];
    int bm0, bn0;
    decode_blk(blockIdx.x, bm0, bn0);
    f32x4 acc[4][4] = {};
    gemm_tile(R, Wo, DMODEL, bm0, bn0, smem, acc);

    const int t = threadIdx.x, lane = t & 63, wave = t >> 6;
    const int wm = (wave & 1) * 64, wn = (wave >> 1) * 64;
    const int fr = lane & 15, quad = lane >> 4;
    #pragma unroll
    for (int i = 0; i < 4; ++i)
        #pragma unroll
        for (int r = 0; r < 4; ++r) {
            int rr = bm0 + wm + i * 16 + quad * 4 + r;
            size_t base = (size_t)rr * DMODEL + bn0 + wn + fr;
            #pragma unroll
            for (int j = 0; j < 4; ++j) out[base + j * 16] = acc[i][j][r];
        }
}

// ---------------------------------------------------------------------------
// P[chunk][bh][e][d] = sum over 256 s of Vt[bh,e,s] * Kt[bh,d,s]  (MFMA).
__global__ __launch_bounds__(256) void kv_mfma(const unsigned short* __restrict__ Vt,
                                               const unsigned short* __restrict__ Kt,
                                               float* __restrict__ P) {
    __shared__ unsigned short ldsV[64 * 64];    // 8 KB
    __shared__ unsigned short ldsK[64 * 64];    // 8 KB
    int bh = blockIdx.x >> 3, chunk = blockIdx.x & 7;
    int t = threadIdx.x, lane = t & 63, wave = t >> 6;
    int fr = lane & 15, quad = lane >> 4;

    unsigned offV[2], offK[2];
    #pragma unroll
    for (int i = 0; i < 2; ++i) {
        int f = t + 256 * i, row = f >> 3, kg = (f & 7) ^ (row & 7);
        unsigned o = ((unsigned)(bh * 64 + row) << 11) + chunk * 256 + kg * 8;
        offV[i] = o; offK[i] = o;
    }

    f32x4 acc[4] = {};
    for (int k0 = 0; k0 < 256; k0 += 64) {
        #pragma unroll
        for (int i = 0; i < 2; ++i)
            load_g2l16(Vt + offV[i] + k0, &ldsV[(t + 256 * i) * 8]);
        #pragma unroll
        for (int i = 0; i < 2; ++i)
            load_g2l16(Kt + offK[i] + k0, &ldsK[(t + 256 * i) * 8]);
        asm volatile("s_waitcnt vmcnt(0)" ::: "memory");
        __syncthreads();

        #pragma unroll
        for (int kh = 0; kh < 2; ++kh) {
            int rowA = wave * 16 + fr;
            int sA = (kh * 4 + quad) ^ (rowA & 7);
            bf16x8 av = *reinterpret_cast<const bf16x8*>(&ldsV[rowA * 64 + sA * 8]);
            #pragma unroll
            for (int j = 0; j < 4; ++j) {
                int rowB = j * 16 + fr;
                int sB = (kh * 4 + quad) ^ (rowB & 7);
                bf16x8 bv = *reinterpret_cast<const bf16x8*>(&ldsK[rowB * 64 + sB * 8]);
                acc[j] = __builtin_amdgcn_mfma_f32_16x16x32_bf16(av, bv, acc[j], 0, 0, 0);
            }
        }
        __syncthreads();
    }
    // C layout: e = wave*16 + quad*4 + r, d = j*16 + fr
    float* Pp = P + ((size_t)chunk * 64 + bh) * 4096;
    #pragma unroll
    for (int j = 0; j < 4; ++j)
        #pragma unroll
        for (int r = 0; r < 4; ++r)
            Pp[(wave * 16 + quad * 4 + r) * 64 + j * 16 + fr] = acc[j][r];
}

// At[idx] (bf16) = sum over 8 chunks of P[chunk][idx], idx in [0, 64*4096)
__global__ __launch_bounds__(256) void reduce_A(const float* __restrict__ P,
                                                unsigned short* __restrict__ At) {
    int idx = blockIdx.x * 256 + threadIdx.x;   // 0 .. 262143
    float s = 0.f;
    #pragma unroll
    for (int c = 0; c < 8; ++c) s += P[(size_t)c * (64 * 4096) + idx];
    At[idx] = f2bf(s);
}

// ---------------------------------------------------------------------------
extern "C" void kernel_launch(void* const* d_in, const int* in_sizes, int n_in,
                              void* d_out, int out_size, void* d_ws, size_t ws_size,
                              hipStream_t stream) {
    const float* xq = (const float*)d_in[0];
    const float* xk = (const float*)d_in[1];
    const float* xv = (const float*)d_in[2];
    const float* Wq = (const float*)d_in[3];
    const float* Wk = (const float*)d_in[4];
    const float* Wv = (const float*)d_in[5];
    const float* Wo = (const float*)d_in[6];
    float* out = (float*)d_out;
    char* ws = (char*)d_ws;

    const size_t MB = 1ull << 20;
    unsigned short* wq_t = (unsigned short*)(ws + 0 * MB);    // 2 MB each
    unsigned short* wk_t = (unsigned short*)(ws + 2 * MB);
    unsigned short* wv_t = (unsigned short*)(ws + 4 * MB);
    unsigned short* wo_b = (unsigned short*)(ws + 6 * MB);    // 2 MB
    unsigned short* Xb   = (unsigned short*)(ws + 8 * MB);    // 48 MB: z0 8-24, z1 24-40, z2 40-56
    unsigned short* Kt   = (unsigned short*)(ws + 56 * MB);   // 16 MB [bh][d][s]
    unsigned short* Vt   = (unsigned short*)(ws + 72 * MB);   // 16 MB [bh][e][s]
    unsigned short* At   = (unsigned short*)(ws + 88 * MB);   // 0.5 MB [bh][e][d]
    // overlays (stream-ordered safe):
    float* P            = (float*)(ws + 24 * MB);             // 8 MB, overlays Xb z1 (dead after proj_kv)
    unsigned short* R   = (unsigned short*)(ws + 40 * MB);    // 16 MB, overlays Xb z2 (dead after proj_kv)

    // weights -> bf16 packs, plus x -> bf16 cast
    prep_w<<<7936, 256, 0, stream>>>(Wq, Wk, Wv, Wo, xq, xk, xv,
                                     wq_t, wk_t, wv_t, wo_b, Xb);

    // K/V projections (fused softmax on K, transposed outputs)
    proj_kv<<<dim3(512, 2), 256, 0, stream>>>(Xb, wk_t, wv_t, Kt, Vt);

    // At = (softmax(K)^T V)^T per bh via MFMA, split-8 + deterministic reduce
    kv_mfma<<<BATCH * HEADS * 8, 256, 0, stream>>>(Vt, Kt, P);
    reduce_A<<<1024, 256, 0, stream>>>(P, At);

    // Q projection fused with xAt -> R [b,h,s,e] flat
    proj_q<<<512, 256, 0, stream>>>(Xb, wq_t, At, R);

    // out = R @ Wo^T (fp32)
    gemm_out<<<512, 256, 0, stream>>>(R, wo_b, out);
}

// Round 7
// 255.861 us; speedup vs baseline: 1.0388x; 1.0388x over previous
//
#include <hip/hip_runtime.h>
#include <cstdint>
#include <cstddef>

// Problem constants
#define DMODEL 1024
#define HEADS  16
#define DHEAD  64
#define BATCH  4
#define SEQ    2048
#define ROWS   (BATCH * SEQ)          // 8192
#define INV_DSCALE 0.3535533905932738f // 1 / 64^(1/4)

typedef float  f32x4  __attribute__((ext_vector_type(4)));
typedef __bf16 bf16x8 __attribute__((ext_vector_type(8)));

__device__ __forceinline__ unsigned short f2bf(float x) {
    union { float f; unsigned u; } c; c.f = x;
    unsigned u = c.u;
    return (unsigned short)((u + 0x7fffu + ((u >> 16) & 1u)) >> 16);
}

// Pack two f32 -> packed 2x bf16 (RNE).
__device__ __forceinline__ unsigned cvt_pk_bf16(float a, float b) {
#if __has_builtin(__builtin_amdgcn_cvt_pk_bf16_f32)
    typedef __bf16 bf16x2_t __attribute__((ext_vector_type(2)));
    union { bf16x2_t v; unsigned u; } c;
    c.v = __builtin_amdgcn_cvt_pk_bf16_f32(a, b);
    return c.u;
#else
    return (unsigned)f2bf(a) | ((unsigned)f2bf(b) << 16);
#endif
}

__device__ __forceinline__ void load_g2l16(const unsigned short* g, unsigned short* l) {
    __builtin_amdgcn_global_load_lds(
        (const __attribute__((address_space(1))) unsigned int*)g,
        (__attribute__((address_space(3))) unsigned int*)l,
        16 /*bytes*/, 0 /*offset*/, 0 /*aux*/);
}

// ---------------------------------------------------------------------------
// Weight prep + x cast (4 unrolled contiguous groups/thread):
//   blocks [0,768)      pack Wq/Wk/Wv -> [n=h*64+d][k=m] bf16
//   blocks [768,1024)   straight-cast Wo (256 blk x 256 thr x 4 = 262144 grp)
//   blocks [1024,4096)  cast xq/xk/xv -> Xb bf16 (1024 blk/z x 256 x 4 = 1048576 grp/z)
__global__ __launch_bounds__(256) void prep_w(const float* __restrict__ W0,
                                              const float* __restrict__ W1,
                                              const float* __restrict__ W2,
                                              const float* __restrict__ Wo,
                                              const float* __restrict__ Xq,
                                              const float* __restrict__ Xk,
                                              const float* __restrict__ Xv,
                                              unsigned short* __restrict__ T0,
                                              unsigned short* __restrict__ T1,
                                              unsigned short* __restrict__ T2,
                                              unsigned short* __restrict__ To,
                                              unsigned short* __restrict__ Xb) {
    __shared__ float tile[64][68];
    int blk = blockIdx.x;
    int t = threadIdx.x;
    if (blk < 768) {
        int w = blk >> 8, h = (blk >> 4) & 15, mb = blk & 15;
        const float* W = w == 0 ? W0 : (w == 1 ? W1 : W2);
        unsigned short* T = w == 0 ? T0 : (w == 1 ? T1 : T2);
        #pragma unroll
        for (int i = 0; i < 4; ++i) {
            int f = t + 256 * i;
            int m = f >> 4, dg = (f & 15) * 4;
            *(float4*)&tile[m][dg] = *(const float4*)&W[((size_t)(h * 16 + mb) * 64 + m) * 64 + dg];
        }
        __syncthreads();
        #pragma unroll
        for (int i = 0; i < 2; ++i) {
            int f = t + 256 * i;
            int d = f >> 3, mg = f & 7;
            ushort4 a, b;
            a.x = f2bf(tile[mg * 8 + 0][d]); a.y = f2bf(tile[mg * 8 + 1][d]);
            a.z = f2bf(tile[mg * 8 + 2][d]); a.w = f2bf(tile[mg * 8 + 3][d]);
            b.x = f2bf(tile[mg * 8 + 4][d]); b.y = f2bf(tile[mg * 8 + 5][d]);
            b.z = f2bf(tile[mg * 8 + 6][d]); b.w = f2bf(tile[mg * 8 + 7][d]);
            unsigned short* dst = T + (size_t)(h * 64 + d) * DMODEL + mb * 64 + mg * 8;
            *(ushort4*)dst = a; *(ushort4*)(dst + 4) = b;
        }
    } else if (blk < 1024) {
        // Wo cast: 256 blocks x 256 thr x 4 float4-groups = 262144 (= 1024*1024/4)
        int wb = blk - 768;
        #pragma unroll
        for (int u = 0; u < 4; ++u) {
            int i = wb * 1024 + u * 256 + t;
            float4 v = ((const float4*)Wo)[i];
            ushort4 o;
            o.x = f2bf(v.x); o.y = f2bf(v.y); o.z = f2bf(v.z); o.w = f2bf(v.w);
            ((ushort4*)To)[i] = o;
        }
    } else {
        // x cast: 1024 blocks per z, 4 contiguous 8-elem groups per thread
        // coverage: 1024 * 256 * 4 = 1048576 groups = 8388608 elems per z ✓
        int bb = blk - 1024;
        int w = bb >> 10;                       // z
        int chunk = bb & 1023;
        const float* X = w == 0 ? Xq : (w == 1 ? Xk : Xv);
        unsigned short* D = Xb + (size_t)w * ROWS * DMODEL;
        #pragma unroll
        for (int u = 0; u < 4; ++u) {
            size_t g = (size_t)chunk * 1024 + u * 256 + t;   // [0, 1048576)
            const float4* src = (const float4*)X + g * 2;
            float4 a = src[0], bv = src[1];
            uint4 pk;
            pk.x = cvt_pk_bf16(a.x, a.y);
            pk.y = cvt_pk_bf16(a.z, a.w);
            pk.z = cvt_pk_bf16(bv.x, bv.y);
            pk.w = cvt_pk_bf16(bv.z, bv.w);
            ((uint4*)D)[g] = pk;
        }
    }
}

// ---------------------------------------------------------------------------
// m97-structure GEMM tile: 128x128, BK=64, 4 waves each 64x64 (4x4 of
// 16x16x32). XOR swizzle: LDS slot (row, s) holds global k-group s ^ (row&7).
// A and B both bf16 in global, staged via global_load_lds width-16.
__device__ __forceinline__ void gemm_tile(const unsigned short* __restrict__ Ap,
                                          const unsigned short* __restrict__ Bp,
                                          int K, int bm0, int bn0,
                                          unsigned short* smem, f32x4 acc[4][4]) {
    unsigned short* ldsA = smem;            // 128*64 u16 = 16 KB
    unsigned short* ldsB = smem + 8192;     // 128*64 u16 = 16 KB

    const int t    = threadIdx.x;
    const int lane = t & 63;
    const int wave = t >> 6;
    const int wm   = (wave & 1) * 64;
    const int wn   = (wave >> 1) * 64;
    const int fr   = lane & 15;
    const int quad = lane >> 4;

    unsigned offA[4], offB[4];
    #pragma unroll
    for (int i = 0; i < 4; ++i) {
        int f = t + 256 * i, row = f >> 3, kg = (f & 7) ^ (row & 7);
        offA[i] = (unsigned)(bm0 + row) * K + kg * 8;
        offB[i] = (unsigned)(bn0 + row) * K + kg * 8;
    }

    for (int k0 = 0; k0 < K; k0 += 64) {
        #pragma unroll
        for (int i = 0; i < 4; ++i)
            load_g2l16(Ap + offA[i] + k0, &ldsA[(t + 256 * i) * 8]);
        #pragma unroll
        for (int i = 0; i < 4; ++i)
            load_g2l16(Bp + offB[i] + k0, &ldsB[(t + 256 * i) * 8]);
        asm volatile("s_waitcnt vmcnt(0)" ::: "memory");
        __syncthreads();

        bf16x8 af[4][2], bfr[4][2];
        #pragma unroll
        for (int i = 0; i < 4; ++i) {
            int row = wm + i * 16 + fr;
            #pragma unroll
            for (int kh = 0; kh < 2; ++kh) {
                int s = (kh * 4 + quad) ^ (row & 7);
                af[i][kh] = *reinterpret_cast<const bf16x8*>(&ldsA[row * 64 + s * 8]);
            }
        }
        #pragma unroll
        for (int j = 0; j < 4; ++j) {
            int row = wn + j * 16 + fr;
            #pragma unroll
            for (int kh = 0; kh < 2; ++kh) {
                int s = (kh * 4 + quad) ^ (row & 7);
                bfr[j][kh] = *reinterpret_cast<const bf16x8*>(&ldsB[row * 64 + s * 8]);
            }
        }
        #pragma unroll
        for (int kh = 0; kh < 2; ++kh)
            #pragma unroll
            for (int i = 0; i < 4; ++i)
                #pragma unroll
                for (int j = 0; j < 4; ++j)
                    acc[i][j] = __builtin_amdgcn_mfma_f32_16x16x32_bf16(af[i][kh], bfr[j][kh], acc[i][j], 0, 0, 0);

        __syncthreads();
    }
}

// Fused 64-wide head-group softmax over the wave's 4 j-frags (one head).
__device__ __forceinline__ void softmax4(float v[4]) {
    #pragma unroll
    for (int j = 0; j < 4; ++j) v[j] *= INV_DSCALE;
    float m = fmaxf(fmaxf(v[0], v[1]), fmaxf(v[2], v[3]));
    #pragma unroll
    for (int off = 8; off; off >>= 1) m = fmaxf(m, __shfl_xor(m, off, 16));
    float s = 0.f;
    #pragma unroll
    for (int j = 0; j < 4; ++j) { v[j] = __expf(v[j] - m); s += v[j]; }
    #pragma unroll
    for (int off = 8; off; off >>= 1) s += __shfl_xor(s, off, 16);
    float inv = 1.0f / s;
    #pragma unroll
    for (int j = 0; j < 4; ++j) v[j] *= inv;
}

// XCD-aware decode for 512 blocks (64 m-blocks x 8 n-blocks of a 128x128 tile)
__device__ __forceinline__ void decode_blk(int flat, int& bm0, int& bn0) {
    int xcd = flat & 7, idx = flat >> 3;        // idx in [0,64)
    bm0 = (xcd * 8 + (idx >> 3)) * 128;
    bn0 = (idx & 7) * 128;
}

// ---------------------------------------------------------------------------
// K/V projections. y=0 -> z=1: K -> softmax -> TRANSPOSED Kt[bh][d][s].
// y=1 -> z=2: V -> TRANSPOSED Vt[bh][e][s].
__global__ __launch_bounds__(256, 2) void proj_kv(const unsigned short* __restrict__ Xb,
                                                  const unsigned short* __restrict__ wk,
                                                  const unsigned short* __restrict__ wv,
                                                  unsigned short* __restrict__ Kt,
                                                  unsigned short* __restrict__ Vt) {
    __shared__ unsigned short smem[17408];      // gemm staging (32 KB), then Ct (128*136)
    int z = blockIdx.y + 1;
    const unsigned short* A = Xb + (size_t)z * ROWS * DMODEL;
    const unsigned short* B = (z == 1) ? wk : wv;
    int bm0, bn0;
    decode_blk(blockIdx.x, bm0, bn0);

    f32x4 acc[4][4] = {};
    gemm_tile(A, B, DMODEL, bm0, bn0, smem, acc);

    const int t    = threadIdx.x;
    const int lane = t & 63;
    const int wave = t >> 6;
    const int wm   = (wave & 1) * 64;
    const int wn   = (wave >> 1) * 64;
    const int fr   = lane & 15;
    const int quad = lane >> 4;
    bool do_sm = (z == 1);

    // transpose epilogue: Ct[col][s_local], pitch 136 (16B-aligned rows)
    unsigned short* Ct = smem;              // 128*136 u16 = 34.8 KB
    #pragma unroll
    for (int i = 0; i < 4; ++i)
        #pragma unroll
        for (int r = 0; r < 4; ++r) {
            float v[4];
            #pragma unroll
            for (int j = 0; j < 4; ++j) v[j] = acc[i][j][r];
            if (do_sm) softmax4(v);
            int rr = wm + i * 16 + quad * 4 + r;          // s_local 0..127
            #pragma unroll
            for (int j = 0; j < 4; ++j) {
                int cc = wn + j * 16 + fr;                // col 0..127
                Ct[cc * 136 + rr] = f2bf(v[j]);
            }
        }
    __syncthreads();
    // coalesced-per-row copy out: thread t handles col c = t>>1, s-half (t&1)*64
    unsigned short* T = (z == 1) ? Kt : Vt;
    int c = t >> 1, sh = (t & 1) * 64;
    int col = bn0 + c, h = col >> 6, d = col & 63;
    int b = bm0 >> 11, s0 = bm0 & 2047;
    unsigned short* dst = T + (((size_t)(b * 16 + h) * 64 + d) << 11) + s0 + sh;
    const unsigned short* src = &smem[c * 136 + sh];
    #pragma unroll
    for (int k = 0; k < 8; ++k)
        *(uint4*)(dst + k * 8) = *(const uint4*)(src + k * 8);
}

// ---------------------------------------------------------------------------
// Q projection FUSED with xAt: R[bh][s][e] = softmax(Q)[s,:] . At[bh][e,:]
// Each block: 128 rows x 2 heads. Qs -> LDS (swizzled), At staged via
// global_load_lds (pre-swizzled source), 32 MFMA/wave epilogue, write R.
__global__ __launch_bounds__(256, 2) void proj_q(const unsigned short* __restrict__ Xb,
                                                 const unsigned short* __restrict__ wq,
                                                 const unsigned short* __restrict__ At,
                                                 unsigned short* __restrict__ R) {
    __shared__ unsigned short smem[24576];   // 48 KB: 32 KB staging/Qs + 16 KB At
    int bm0, bn0;
    decode_blk(blockIdx.x, bm0, bn0);

    f32x4 acc[4][4] = {};
    gemm_tile(Xb, wq, DMODEL, bm0, bn0, smem, acc);

    const int t = threadIdx.x, lane = t & 63, wave = t >> 6;
    const int wm = (wave & 1) * 64, wn = (wave >> 1) * 64;
    const int fr = lane & 15, quad = lane >> 4;
    const int b = bm0 >> 11, s0 = bm0 & 2047;
    const int h0 = bn0 >> 6;                 // first of two heads in this block
    const int bh_base = b * 16 + h0;

    unsigned short* Qs = smem;               // [128][128] u16, XOR-swizzled per 64-col panel
    unsigned short* ldsAt = smem + 16384;    // [2][64*64]

    // stage At for the block's two heads (swizzled source, linear dest)
    #pragma unroll
    for (int i = 0; i < 4; ++i) {
        int f = t + 256 * i;                 // 0..1023 groups of 8
        int hd = f >> 9, row = (f >> 3) & 63, kg = (f & 7) ^ (row & 7);
        load_g2l16(At + (size_t)(bh_base + hd) * 4096 + row * 64 + kg * 8,
                   &ldsAt[f * 8]);
    }

    // softmax + write Qs tile to LDS (swizzled within each 64-col panel)
    #pragma unroll
    for (int i = 0; i < 4; ++i)
        #pragma unroll
        for (int r = 0; r < 4; ++r) {
            float v[4];
            #pragma unroll
            for (int j = 0; j < 4; ++j) v[j] = acc[i][j][r];
            softmax4(v);
            int row = wm + i * 16 + quad * 4 + r;
            #pragma unroll
            for (int j = 0; j < 4; ++j) {
                int c = wn + j * 16 + fr;
                int cs = (c & 0x47) | (((((c >> 3) & 7) ^ (row & 7))) << 3);
                Qs[row * 128 + cs] = f2bf(v[j]);
            }
        }
    asm volatile("s_waitcnt vmcnt(0)" ::: "memory");
    __syncthreads();

    // R-tile = Qs(64 rows x 64 d, head hw) x At[hw] ([e][d] operand)
    const int hw = wn >> 6;
    f32x4 racc[4][4] = {};
    #pragma unroll
    for (int kh = 0; kh < 2; ++kh) {
        bf16x8 aq[4], bt[4];
        #pragma unroll
        for (int i = 0; i < 4; ++i) {
            int row = wm + i * 16 + fr;
            int s = (kh * 4 + quad) ^ (row & 7);
            aq[i] = *reinterpret_cast<const bf16x8*>(&Qs[row * 128 + wn + s * 8]);
        }
        #pragma unroll
        for (int j = 0; j < 4; ++j) {
            int e = j * 16 + fr;
            int s = (kh * 4 + quad) ^ (e & 7);
            bt[j] = *reinterpret_cast<const bf16x8*>(&ldsAt[(hw << 12) + e * 64 + s * 8]);
        }
        #pragma unroll
        for (int i = 0; i < 4; ++i)
            #pragma unroll
            for (int j = 0; j < 4; ++j)
                racc[i][j] = __builtin_amdgcn_mfma_f32_16x16x32_bf16(aq[i], bt[j], racc[i][j], 0, 0, 0);
    }

    // write R flat [b,h,s,e]
    size_t bh = (size_t)(bh_base + hw);
    #pragma unroll
    for (int i = 0; i < 4; ++i)
        #pragma unroll
        for (int r = 0; r < 4; ++r) {
            int rr = wm + i * 16 + quad * 4 + r;         // s_local within 128
            size_t base = (bh << 17) + (size_t)(s0 + rr) * 64;
            #pragma unroll
            for (int j = 0; j < 4; ++j)
                R[base + j * 16 + fr] = f2bf(racc[i][j][r]);
        }
}

// out = R (bf16 [8192,1024] flat) @ Wo^T -> fp32
__global__ __launch_bounds__(256, 2) void gemm_out(const unsigned short* __restrict__ R,
                                                   const unsigned short* __restrict__ Wo,
                                                   float* __restrict__ out) {
    __shared__ unsigned short smem[16384];
    int bm0, bn0;
    decode_blk(blockIdx.x, bm0, bn0);
    f32x4 acc[4][4] = {};
    gemm_tile(R, Wo, DMODEL, bm0, bn0, smem, acc);

    const int t = threadIdx.x, lane = t & 63, wave = t >> 6;
    const int wm = (wave & 1) * 64, wn = (wave >> 1) * 64;
    const int fr = lane & 15, quad = lane >> 4;
    #pragma unroll
    for (int i = 0; i < 4; ++i)
        #pragma unroll
        for (int r = 0; r < 4; ++r) {
            int rr = bm0 + wm + i * 16 + quad * 4 + r;
            size_t base = (size_t)rr * DMODEL + bn0 + wn + fr;
            #pragma unroll
            for (int j = 0; j < 4; ++j) out[base + j * 16] = acc[i][j][r];
        }
}

// ---------------------------------------------------------------------------
// P[chunk][bh][e][d] = sum over 256 s of Vt[bh,e,s] * Kt[bh,d,s]  (MFMA).
__global__ __launch_bounds__(256) void kv_mfma(const unsigned short* __restrict__ Vt,
                                               const unsigned short* __restrict__ Kt,
                                               float* __restrict__ P) {
    __shared__ unsigned short ldsV[64 * 64];    // 8 KB
    __shared__ unsigned short ldsK[64 * 64];    // 8 KB
    int bh = blockIdx.x >> 3, chunk = blockIdx.x & 7;
    int t = threadIdx.x, lane = t & 63, wave = t >> 6;
    int fr = lane & 15, quad = lane >> 4;

    unsigned offV[2], offK[2];
    #pragma unroll
    for (int i = 0; i < 2; ++i) {
        int f = t + 256 * i, row = f >> 3, kg = (f & 7) ^ (row & 7);
        unsigned o = ((unsigned)(bh * 64 + row) << 11) + chunk * 256 + kg * 8;
        offV[i] = o; offK[i] = o;
    }

    f32x4 acc[4] = {};
    for (int k0 = 0; k0 < 256; k0 += 64) {
        #pragma unroll
        for (int i = 0; i < 2; ++i)
            load_g2l16(Vt + offV[i] + k0, &ldsV[(t + 256 * i) * 8]);
        #pragma unroll
        for (int i = 0; i < 2; ++i)
            load_g2l16(Kt + offK[i] + k0, &ldsK[(t + 256 * i) * 8]);
        asm volatile("s_waitcnt vmcnt(0)" ::: "memory");
        __syncthreads();

        #pragma unroll
        for (int kh = 0; kh < 2; ++kh) {
            int rowA = wave * 16 + fr;
            int sA = (kh * 4 + quad) ^ (rowA & 7);
            bf16x8 av = *reinterpret_cast<const bf16x8*>(&ldsV[rowA * 64 + sA * 8]);
            #pragma unroll
            for (int j = 0; j < 4; ++j) {
                int rowB = j * 16 + fr;
                int sB = (kh * 4 + quad) ^ (rowB & 7);
                bf16x8 bv = *reinterpret_cast<const bf16x8*>(&ldsK[rowB * 64 + sB * 8]);
                acc[j] = __builtin_amdgcn_mfma_f32_16x16x32_bf16(av, bv, acc[j], 0, 0, 0);
            }
        }
        __syncthreads();
    }
    // C layout: e = wave*16 + quad*4 + r, d = j*16 + fr
    float* Pp = P + ((size_t)chunk * 64 + bh) * 4096;
    #pragma unroll
    for (int j = 0; j < 4; ++j)
        #pragma unroll
        for (int r = 0; r < 4; ++r)
            Pp[(wave * 16 + quad * 4 + r) * 64 + j * 16 + fr] = acc[j][r];
}

// At[idx] (bf16) = sum over 8 chunks of P[chunk][idx], idx in [0, 64*4096)
__global__ __launch_bounds__(256) void reduce_A(const float* __restrict__ P,
                                                unsigned short* __restrict__ At) {
    int idx = blockIdx.x * 256 + threadIdx.x;   // 0 .. 262143
    float s = 0.f;
    #pragma unroll
    for (int c = 0; c < 8; ++c) s += P[(size_t)c * (64 * 4096) + idx];
    At[idx] = f2bf(s);
}

// ---------------------------------------------------------------------------
extern "C" void kernel_launch(void* const* d_in, const int* in_sizes, int n_in,
                              void* d_out, int out_size, void* d_ws, size_t ws_size,
                              hipStream_t stream) {
    const float* xq = (const float*)d_in[0];
    const float* xk = (const float*)d_in[1];
    const float* xv = (const float*)d_in[2];
    const float* Wq = (const float*)d_in[3];
    const float* Wk = (const float*)d_in[4];
    const float* Wv = (const float*)d_in[5];
    const float* Wo = (const float*)d_in[6];
    float* out = (float*)d_out;
    char* ws = (char*)d_ws;

    const size_t MB = 1ull << 20;
    unsigned short* wq_t = (unsigned short*)(ws + 0 * MB);    // 2 MB each
    unsigned short* wk_t = (unsigned short*)(ws + 2 * MB);
    unsigned short* wv_t = (unsigned short*)(ws + 4 * MB);
    unsigned short* wo_b = (unsigned short*)(ws + 6 * MB);    // 2 MB
    unsigned short* Xb   = (unsigned short*)(ws + 8 * MB);    // 48 MB: z0 8-24, z1 24-40, z2 40-56
    unsigned short* Kt   = (unsigned short*)(ws + 56 * MB);   // 16 MB [bh][d][s]
    unsigned short* Vt   = (unsigned short*)(ws + 72 * MB);   // 16 MB [bh][e][s]
    unsigned short* At   = (unsigned short*)(ws + 88 * MB);   // 0.5 MB [bh][e][d]
    // overlays (stream-ordered safe):
    float* P            = (float*)(ws + 24 * MB);             // 8 MB, overlays Xb z1 (dead after proj_kv)
    unsigned short* R   = (unsigned short*)(ws + 40 * MB);    // 16 MB, overlays Xb z2 (dead after proj_kv)

    // weights -> bf16 packs, plus x -> bf16 cast
    prep_w<<<4096, 256, 0, stream>>>(Wq, Wk, Wv, Wo, xq, xk, xv,
                                     wq_t, wk_t, wv_t, wo_b, Xb);

    // K/V projections (fused softmax on K, transposed outputs)
    proj_kv<<<dim3(512, 2), 256, 0, stream>>>(Xb, wk_t, wv_t, Kt, Vt);

    // At = (softmax(K)^T V)^T per bh via MFMA, split-8 + deterministic reduce
    kv_mfma<<<BATCH * HEADS * 8, 256, 0, stream>>>(Vt, Kt, P);
    reduce_A<<<1024, 256, 0, stream>>>(P, At);

    // Q projection fused with xAt -> R [b,h,s,e] flat
    proj_q<<<512, 256, 0, stream>>>(Xb, wq_t, At, R);

    // out = R @ Wo^T (fp32)
    gemm_out<<<512, 256, 0, stream>>>(R, wo_b, out);
}